// Round 4
// baseline (36024.673 us; speedup 1.0000x reference)
//
#include <hip/hip_runtime.h>
#include <hip/hip_cooperative_groups.h>
#include <math.h>

namespace cg = cooperative_groups;

#define HIDDEN 512
#define EN 256
#define ET 512
#define VOCAB_N 300
#define VOCAB_T 10000
#define ATTN 50
#define V_OUT (VOCAB_T + ATTN + 3)   // 10053
#define EOF_N (VOCAB_N - 1)          // 299
#define EOF_T (VOCAB_T - 1)          // 9999
#define SOS 0
#define CONF 0.9f
#define SM_VAL (0.1f / (float)(V_OUT - 2))
#define BB 32
#define LL 128

#define GSG 8     // gates split-K (K=1280 -> 160/split, 5 chunks of 32)
#define GSL 6     // logits split-K (K=1536 -> 256/split, 8 chunks of 32)
#define JBL 40    // logits j-blocks (40*256 >= 10053)
#define NBLK 256  // cooperative grid: 1 block/CU

struct KArgs {
    const int *n_t, *t_t, *p_t;
    const float *embN, *embT, *w_ih, *w_hh, *b_ih, *b_hh;
    const float *Wh_w, *Wh_b, *v_w, *v_b, *Wg_w, *Wg_b, *Ws_w, *Ws_b;
    float *out;
    float *hs, *c, *xbuf, *xg, *a_out, *s_t, *tl_partial, *gl;
};

__global__ __launch_bounds__(256, 2) void k_persist(KArgs a) {
    cg::grid_group grid = cg::this_grid();
    __shared__ __align__(16) float smem[16384];   // 64 KB, re-purposed per phase
    const int bx = blockIdx.x;
    const int tid = threadIdx.x;

    // ================= init: zero hs,c; xg = [embN[SOS]|embT[SOS]|h=0] =========
    {
        int gidx = bx * 256 + tid, gs = NBLK * 256;
        for (int k = gidx; k < BB * LL * 512; k += gs) a.hs[k] = 0.0f;
        for (int k = gidx; k < BB * 512; k += gs) a.c[k] = 0.0f;
        for (int k = gidx; k < BB * 1280; k += gs) {
            int kk = k % 1280;
            float v;
            if (kk < 256)      v = a.embN[kk];
            else if (kk < 768) v = a.embT[kk - 256];
            else               v = 0.0f;
            a.xg[k] = v;
        }
    }
    grid.sync();

    for (int it = 0; it < LL; ++it) {
        // ============ phase 1: gates GEMM (all 256 blocks) =====================
        // gpart[s][b][2048] = xg[32,1280] @ [w_ih|w_hh]^T ; jt=(bx&31)*64, s=bx>>5
        {
            float (*Ws)[64] = (float(*)[64])smem;            // 32*64
            float (*Xs)[32] = (float(*)[32])(smem + 2048);   // 32*32
            const int jt = (bx & 31) * 64;
            const int s  = bx >> 5;
            const int jq = tid & 15;          // j0 = jq*4
            const int bq = tid >> 4;          // b0 = bq*2
            const int wjr = tid & 31, wkc = (tid >> 5) * 4;
            const int xb  = tid & 31, xk  = (tid >> 5) * 4;
            float4 wreg[2], xreg;
            float acc[2][4] = {{0.f,0.f,0.f,0.f},{0.f,0.f,0.f,0.f}};
            const int kbase = s * 160;
            {   // prefetch chunk 0
                int k0 = kbase;
                int kg = k0 + wkc;
                #pragma unroll
                for (int r = 0; r < 2; ++r) {
                    int row = jt + wjr + r * 32;
                    wreg[r] = (kg < 768) ? *(const float4*)(a.w_ih + (size_t)row * 768 + kg)
                                         : *(const float4*)(a.w_hh + (size_t)row * 512 + (kg - 768));
                }
                xreg = *(const float4*)(a.xg + xb * 1280 + k0 + xk);
            }
            for (int ch = 0; ch < 5; ++ch) {
                __syncthreads();
                #pragma unroll
                for (int r = 0; r < 2; ++r) {
                    Ws[wkc+0][wjr + r*32] = wreg[r].x;
                    Ws[wkc+1][wjr + r*32] = wreg[r].y;
                    Ws[wkc+2][wjr + r*32] = wreg[r].z;
                    Ws[wkc+3][wjr + r*32] = wreg[r].w;
                }
                Xs[xk+0][xb] = xreg.x; Xs[xk+1][xb] = xreg.y;
                Xs[xk+2][xb] = xreg.z; Xs[xk+3][xb] = xreg.w;
                __syncthreads();
                if (ch < 4) {
                    int k0 = kbase + (ch + 1) * 32;
                    int kg = k0 + wkc;
                    #pragma unroll
                    for (int r = 0; r < 2; ++r) {
                        int row = jt + wjr + r * 32;
                        wreg[r] = (kg < 768) ? *(const float4*)(a.w_ih + (size_t)row * 768 + kg)
                                             : *(const float4*)(a.w_hh + (size_t)row * 512 + (kg - 768));
                    }
                    xreg = *(const float4*)(a.xg + xb * 1280 + k0 + xk);
                }
                #pragma unroll 4
                for (int kk = 0; kk < 32; ++kk) {
                    float4 w = *(const float4*)&Ws[kk][jq * 4];
                    float2 x = *(const float2*)&Xs[kk][bq * 2];
                    acc[0][0] += x.x*w.x; acc[0][1] += x.x*w.y; acc[0][2] += x.x*w.z; acc[0][3] += x.x*w.w;
                    acc[1][0] += x.y*w.x; acc[1][1] += x.y*w.y; acc[1][2] += x.y*w.z; acc[1][3] += x.y*w.w;
                }
            }
            #pragma unroll
            for (int r = 0; r < 2; ++r) {
                float4 v = make_float4(acc[r][0], acc[r][1], acc[r][2], acc[r][3]);
                *(float4*)(a.gl + ((size_t)s * 32 + bq * 2 + r) * 2048 + jt + jq * 4) = v;
            }
        }
        grid.sync();

        // ============ phase 2: cell (blocks 0..31) =============================
        if (bx < 32) {
            float* h_s = smem;          // 512
            float* c_s = smem + 512;    // 512
            float* red = smem + 1024;   // 256
            const int b = bx;
            int parent = (it == 0) ? 0 : a.p_t[b * LL + it - 1];
            for (int k = tid; k < 512; k += 256)
                a.xbuf[b * 1536 + 1024 + k] = a.hs[((size_t)b * LL + parent) * 512 + k];
            for (int jj = tid; jj < 512; jj += 256) {
                float ig = a.b_ih[jj]        + a.b_hh[jj];
                float fg = a.b_ih[512 + jj]  + a.b_hh[512 + jj];
                float gg = a.b_ih[1024 + jj] + a.b_hh[1024 + jj];
                float og = a.b_ih[1536 + jj] + a.b_hh[1536 + jj];
                #pragma unroll
                for (int s = 0; s < GSG; ++s) {
                    const float* gp = a.gl + ((size_t)s * 32 + b) * 2048;
                    ig += gp[jj]; fg += gp[512 + jj]; gg += gp[1024 + jj]; og += gp[1536 + jj];
                }
                float si = 1.0f / (1.0f + expf(-ig));
                float sf = 1.0f / (1.0f + expf(-fg));
                float so = 1.0f / (1.0f + expf(-og));
                float cn = sf * a.c[b * 512 + jj] + si * tanhf(gg);
                float hn = so * tanhf(cn);
                c_s[jj] = cn; h_s[jj] = hn;
                a.c[b * 512 + jj] = cn;
            }
            __syncthreads();
            int nn = a.n_t[b * LL + it], tn = a.t_t[b * LL + it];  // inputs for it+1
            for (int k = tid; k < 512; k += 256) {
                float hv = h_s[k], cv = c_s[k];
                a.hs[((size_t)b * LL + it) * 512 + k] = hv;
                a.xbuf[b * 1536 + k] = hv;
                a.xbuf[b * 1536 + 512 + k] = cv;
                a.xg[b * 1280 + 768 + k] = hv;
                a.xg[b * 1280 + 256 + k] = a.embT[(size_t)tn * 512 + k];
            }
            a.xg[b * 1280 + tid] = a.embN[(size_t)nn * 256 + tid];
            float acc = 0.0f;
            for (int k = tid; k < 512; k += 256) acc += h_s[k] * a.Ws_w[k];
            for (int k = tid; k < 512; k += 256) acc += c_s[k] * a.Ws_w[512 + k];
            red[tid] = acc;
            __syncthreads();
            for (int s2 = 128; s2 > 0; s2 >>= 1) {
                if (tid < s2) red[tid] += red[tid + s2];
                __syncthreads();
            }
            if (tid == 0) a.s_t[b] = 1.0f / (1.0f + expf(-(red[0] + a.Ws_b[0])));
        }
        grid.sync();

        // ============ phase 3: big (0..239 logits, 240..255 Wh) ================
        if (bx < JBL * GSL) {
            float (*Ws)[256] = (float(*)[256])smem;              // 32*256
            float (*Xs)[32]  = (float(*)[32])(smem + 8192);      // 32*32
            const int jb = bx % JBL, s = bx / JBL;
            const int jt = jb * 256;
            const int jq = tid & 31;
            const int bq = tid >> 5;
            const int wjr = tid & 31, wkc = (tid >> 5) * 4;
            const int xb  = tid & 31, xk  = (tid >> 5) * 4;
            float4 wreg[8], xreg;
            float acc[4][8];
            #pragma unroll
            for (int r = 0; r < 4; ++r)
                #pragma unroll
                for (int q = 0; q < 8; ++q) acc[r][q] = 0.f;
            const int kbase = s * 256;
            {   // prefetch chunk 0
                int k0 = kbase;
                #pragma unroll
                for (int r = 0; r < 8; ++r) {
                    int row = jt + wjr + r * 32;
                    if (row >= V_OUT) row = 0;
                    wreg[r] = *(const float4*)(a.Wg_w + (size_t)row * 1536 + k0 + wkc);
                }
                xreg = *(const float4*)(a.xbuf + xb * 1536 + k0 + xk);
            }
            for (int ch = 0; ch < 8; ++ch) {
                __syncthreads();
                #pragma unroll
                for (int r = 0; r < 8; ++r) {
                    Ws[wkc+0][wjr + r*32] = wreg[r].x;
                    Ws[wkc+1][wjr + r*32] = wreg[r].y;
                    Ws[wkc+2][wjr + r*32] = wreg[r].z;
                    Ws[wkc+3][wjr + r*32] = wreg[r].w;
                }
                Xs[xk+0][xb] = xreg.x; Xs[xk+1][xb] = xreg.y;
                Xs[xk+2][xb] = xreg.z; Xs[xk+3][xb] = xreg.w;
                __syncthreads();
                if (ch < 7) {
                    int k0 = kbase + (ch + 1) * 32;
                    #pragma unroll
                    for (int r = 0; r < 8; ++r) {
                        int row = jt + wjr + r * 32;
                        if (row >= V_OUT) row = 0;
                        wreg[r] = *(const float4*)(a.Wg_w + (size_t)row * 1536 + k0 + wkc);
                    }
                    xreg = *(const float4*)(a.xbuf + xb * 1536 + k0 + xk);
                }
                #pragma unroll 4
                for (int kk = 0; kk < 32; ++kk) {
                    float4 xv = *(const float4*)&Xs[kk][bq * 4];
                    float4 w0 = *(const float4*)&Ws[kk][jq * 4];
                    float4 w1 = *(const float4*)&Ws[kk][128 + jq * 4];
                    acc[0][0] += xv.x*w0.x; acc[0][1] += xv.x*w0.y; acc[0][2] += xv.x*w0.z; acc[0][3] += xv.x*w0.w;
                    acc[0][4] += xv.x*w1.x; acc[0][5] += xv.x*w1.y; acc[0][6] += xv.x*w1.z; acc[0][7] += xv.x*w1.w;
                    acc[1][0] += xv.y*w0.x; acc[1][1] += xv.y*w0.y; acc[1][2] += xv.y*w0.z; acc[1][3] += xv.y*w0.w;
                    acc[1][4] += xv.y*w1.x; acc[1][5] += xv.y*w1.y; acc[1][6] += xv.y*w1.z; acc[1][7] += xv.y*w1.w;
                    acc[2][0] += xv.z*w0.x; acc[2][1] += xv.z*w0.y; acc[2][2] += xv.z*w0.z; acc[2][3] += xv.z*w0.w;
                    acc[2][4] += xv.z*w1.x; acc[2][5] += xv.z*w1.y; acc[2][6] += xv.z*w1.z; acc[2][7] += xv.z*w1.w;
                    acc[3][0] += xv.w*w0.x; acc[3][1] += xv.w*w0.y; acc[3][2] += xv.w*w0.z; acc[3][3] += xv.w*w0.w;
                    acc[3][4] += xv.w*w1.x; acc[3][5] += xv.w*w1.y; acc[3][6] += xv.w*w1.z; acc[3][7] += xv.w*w1.w;
                }
            }
            float* lp = a.gl + (size_t)s * (BB * V_OUT);
            #pragma unroll
            for (int r = 0; r < 4; ++r) {
                float* dst = lp + (size_t)(bq * 4 + r) * V_OUT;
                #pragma unroll
                for (int q = 0; q < 4; ++q) {
                    int j1 = jt + jq * 4 + q;
                    if (j1 < V_OUT) dst[j1] = acc[r][q];
                    int j2 = jt + 128 + jq * 4 + q;
                    if (j2 < V_OUT) dst[j2] = acc[r][4 + q];
                }
            }
        } else {
            // Wh: a_out[b][j] = h[b] . Wh_w[j] + Wh_b[j] ; 16 blocks x 32 cols
            float* h_s = smem;   // [32][512] = 64 KB
            for (int i = tid; i < 32 * 128; i += 256) {
                int b = i >> 7, f4 = i & 127;
                *(float4*)&h_s[b * 512 + f4 * 4] = *(const float4*)(a.xbuf + b * 1536 + f4 * 4);
            }
            __syncthreads();
            const int j = (bx - JBL * GSL) * 32 + (tid & 31);
            const int b0 = (tid >> 5) * 4;
            float ac[4] = {0.f, 0.f, 0.f, 0.f};
            const float* wrow = a.Wh_w + (size_t)j * 512;
            #pragma unroll 4
            for (int k = 0; k < 512; k += 4) {
                float4 w = *(const float4*)(wrow + k);
                #pragma unroll
                for (int r = 0; r < 4; ++r) {
                    float4 x = *(const float4*)(h_s + (b0 + r) * 512 + k);
                    ac[r] += w.x*x.x + w.y*x.y + w.z*x.z + w.w*x.w;
                }
            }
            float bias = a.Wh_b[j];
            #pragma unroll
            for (int r = 0; r < 4; ++r) a.a_out[(b0 + r) * 512 + j] = ac[r] + bias;
        }
        grid.sync();

        // ============ phase 4: scorefinal (blocks 0..31) =======================
        if (bx < 32) {
            float* a_s = smem;                   // 512
            float* sc  = smem + 512;             // 52
            float* mv  = smem + 576;             // 256
            float* sv  = smem + 832;             // 256
            int*   mi  = (int*)(smem + 1088);    // 256
            const int b = bx;
            const int lane = tid & 63, wv = tid >> 6;
            for (int k = tid; k < 512; k += 256) a_s[k] = a.a_out[b * 512 + k];
            __syncthreads();
            for (int w = wv; w < ATTN; w += 4) {
                int idx = it + w - ATTN;
                int idxc = idx < 0 ? 0 : idx;
                bool mask = (idx < 0) || (a.n_t[b * LL + idxc] == EOF_N);
                float sres = -1e20f;
                if (!mask) {
                    const float* mrow = a.hs + ((size_t)b * LL + idxc) * 512;
                    float acc = 0.0f;
                    for (int k = lane; k < 512; k += 64) {
                        float x = a_s[k] + mrow[k];
                        float e = __expf(2.0f * x);
                        acc += a.v_w[k] * (1.0f - 2.0f / (e + 1.0f));
                    }
                    for (int o = 32; o > 0; o >>= 1) acc += __shfl_down(acc, o);
                    sres = acc + a.v_b[0];
                }
                if (lane == 0) sc[w] = sres;
            }
            __syncthreads();
            if (tid == 0) {
                float m = -INFINITY;
                for (int w = 0; w < ATTN; w++) m = fmaxf(m, sc[w]);
                float Z = 0.0f, emax = 0.0f;
                for (int w = 0; w < ATTN; w++) {
                    float e = __expf(sc[w] - m);
                    Z += e;
                    if (e > emax) emax = e;
                }
                sc[50] = emax / Z;   // amax of attn_w
                sc[51] = 1.0f;       // asum
            }
            int t_col = a.t_t[b * LL + it];
            float lmax = -INFINITY; int limax = 0; float lsum = 0.0f;
            for (int j = tid; j < V_OUT; j += 256) {
                float v = a.Wg_b[j];
                #pragma unroll
                for (int s = 0; s < GSL; ++s)
                    v += a.gl[(size_t)s * (BB * V_OUT) + (size_t)b * V_OUT + j];
                lsum += v;
                if (v > lmax) { lmax = v; limax = j; }
                if (j == t_col) smem[1344] = v;
                if (j == EOF_T) smem[1345] = v;
            }
            mv[tid] = lmax; mi[tid] = limax; sv[tid] = lsum;
            __syncthreads();
            for (int s2 = 128; s2 > 0; s2 >>= 1) {
                if (tid < s2) {
                    if (mv[tid + s2] > mv[tid] || (mv[tid + s2] == mv[tid] && mi[tid + s2] < mi[tid])) {
                        mv[tid] = mv[tid + s2]; mi[tid] = mi[tid + s2];
                    }
                    sv[tid] += sv[tid + s2];
                }
                __syncthreads();
            }
            float M = mv[0]; int argJ = mi[0]; float sumL = sv[0];
            __syncthreads();
            float esum = 0.0f;
            for (int j = tid; j < V_OUT; j += 256) {
                float v = a.Wg_b[j];
                #pragma unroll
                for (int s = 0; s < GSL; ++s)
                    v += a.gl[(size_t)s * (BB * V_OUT) + (size_t)b * V_OUT + j];
                esum += expf(v - M);
            }
            sv[tid] = esum;
            __syncthreads();
            for (int s2 = 128; s2 > 0; s2 >>= 1) {
                if (tid < s2) sv[tid] += sv[tid + s2];
                __syncthreads();
            }
            if (tid == 0) {
                float lse = logf(sv[0]);
                float st = a.s_t[b];
                float amax = sc[50], asum = sc[51];
                float max_out = st * (-lse);
                float max_loc = (1.0f - st) * amax;
                bool cond = max_out > max_loc;
                const float CONST_T = CONF * logf(CONF) + 0.1f * logf(SM_VAL);
                float tl; int topi;
                if (!cond) {
                    topi = argJ;
                    float off = M + lse;
                    float out_t = st * (smem[1344] - off);
                    float out_e = st * (smem[1345] - off);
                    float S = st * (sumL - (float)V_OUT * off);
                    tl = CONST_T - (SM_VAL * (S - out_e - out_t) + CONF * out_t);
                } else {
                    topi = 0;
                    float S = (1.0f - st) * asum;
                    tl = CONST_T - SM_VAL * S;
                }
                if (t_col == EOF_T) tl = 0.0f;
                a.tl_partial[it * BB + b] = tl;
                a.out[1 + b * LL + it] = (float)topi;
            }
        }
        grid.sync();
    }

    // ================= final: loss sum (block 0) ===============================
    if (bx == 0) {
        float* r = smem;
        float acc = 0.0f;
        for (int i = tid; i < BB * LL; i += 256) acc += a.tl_partial[i];
        r[tid] = acc;
        __syncthreads();
        for (int s = 128; s > 0; s >>= 1) {
            if (tid < s) r[tid] += r[tid + s];
            __syncthreads();
        }
        if (tid == 0) a.out[0] = r[0];
    }
}

extern "C" void kernel_launch(void* const* d_in, const int* in_sizes, int n_in,
                              void* d_out, int out_size, void* d_ws, size_t ws_size,
                              hipStream_t stream) {
    KArgs args;
    args.n_t  = (const int*)d_in[0];
    args.t_t  = (const int*)d_in[1];
    args.p_t  = (const int*)d_in[2];
    args.embN = (const float*)d_in[3];
    args.embT = (const float*)d_in[4];
    args.w_ih = (const float*)d_in[5];
    args.w_hh = (const float*)d_in[6];
    args.b_ih = (const float*)d_in[7];
    args.b_hh = (const float*)d_in[8];
    args.Wh_w = (const float*)d_in[9];
    args.Wh_b = (const float*)d_in[10];
    args.v_w  = (const float*)d_in[11];
    args.v_b  = (const float*)d_in[12];
    args.Wg_w = (const float*)d_in[13];
    args.Wg_b = (const float*)d_in[14];
    args.Ws_w = (const float*)d_in[15];
    args.Ws_b = (const float*)d_in[16];
    args.out  = (float*)d_out;

    // workspace layout (floats); gl aliases gpart & lpart (sync-separated phases)
    float* ws = (float*)d_ws;
    args.hs         = ws;                   // 2,097,152
    args.c          = args.hs + 2097152;    // 16,384
    args.xbuf       = args.c + 16384;       // 32*1536 = 49,152  [h|c|hcp]
    args.xg         = args.xbuf + 49152;    // 32*1280 = 40,960  [embN|embT|h]
    args.a_out      = args.xg + 40960;      // 16,384
    args.s_t        = args.a_out + 16384;   // 32
    args.tl_partial = args.s_t + 32;        // 4,096
    args.gl         = args.tl_partial + 4096; // max(GSG*32*2048, GSL*32*V_OUT) = 1,930,176
    // total = 4,154,336 floats = 16.62 MB

    void* params[] = { (void*)&args };
    hipLaunchCooperativeKernel((const void*)k_persist, dim3(NBLK), dim3(256),
                               params, 0u, stream);
}

// Round 5
// 22389.755 us; speedup vs baseline: 1.6090x; 1.6090x over previous
//
#include <hip/hip_runtime.h>
#include <math.h>

#define VOCAB_N 300
#define VOCAB_T 10000
#define ATTN 50
#define V_OUT (VOCAB_T + ATTN + 3)   // 10053
#define EOF_N (VOCAB_N - 1)          // 299
#define EOF_T (VOCAB_T - 1)          // 9999
#define SOS 0
#define CONF 0.9f
#define SM_VAL (0.1f / (float)(V_OUT - 2))
#define BB 32
#define LL 128

#define GSG 5                 // gates split-K: K=1280 -> 256/split
#define GSL 6                 // logits split-K: K=1536 -> 256/split
#define JBG 8                 // gates j-blocks (8*256 = 2048)
#define JBL 40                // logits j-blocks (40*256 >= 10053)
#define NB_GATES (JBG*GSG)    // 40
#define NB_WH 16
#define NB_LOGITS (JBL*GSL)   // 240
#define GROUP (32 + NB_GATES + NB_WH + NB_LOGITS + 32)   // 360
#define NBLOCKS (NB_GATES + GROUP*LL + 1)                // 46121

struct KArgs {
    const int *n_t, *t_t, *p_t;
    const float *embN, *embT, *w_ih, *w_hh, *b_ih, *b_hh;
    const float *Wh_w, *Wh_b, *v_w, *v_b, *Wg_w, *Wg_b, *Ws_w, *Ws_b;
    float *out;
    float *hs, *c, *xbuf, *xg, *a_out, *s_t, *tl_partial, *gpart, *lpart;
    unsigned *ctr;   // [0]=G (gates done) [1]=C (cell done) [2]=B2 (logits+Wh done) [3]=S (scorefinal done)
};

// consumer side: spin (relaxed) then acquire
__device__ __forceinline__ void wait_ge(unsigned* ctr, unsigned target, int tid) {
    if (tid == 0) {
        if (target > 0) {
            while (__hip_atomic_load(ctr, __ATOMIC_RELAXED, __HIP_MEMORY_SCOPE_AGENT) < target)
                __builtin_amdgcn_s_sleep(8);
        }
        __threadfence();   // acquire: invalidate stale cached lines
    }
    __syncthreads();
}

// producer side: all block stores drained by __syncthreads (vmcnt0 before s_barrier),
// then release-fence (L2 writeback) + device-scope atomic signal
__device__ __forceinline__ void signal(unsigned* ctr, int tid) {
    __syncthreads();
    if (tid == 0) { __threadfence(); atomicAdd(ctr, 1u); }
}

// ---- shared GEMM tile: BN=256 j-cols x 32 b, K-chunk 8x32 (proven R3/R4 body) ----
template<bool GATES>
__device__ __forceinline__ void gemm_tile(
        const float* __restrict__ Wfull,
        const float* __restrict__ wih, const float* __restrict__ whh,
        const float* __restrict__ X, const int xstride,
        const int jt, const int kbase,
        float* __restrict__ outp, const int ostride,
        float* smem, const int tid) {
    float (*Ws)[256] = (float(*)[256])smem;             // 32 x 256
    float (*Xs)[32]  = (float(*)[32])(smem + 8192);     // 32 x 32
    const int jq = tid & 31;
    const int bq = tid >> 5;
    const int wjr = tid & 31, wkc = (tid >> 5) * 4;
    const int xb  = tid & 31, xk  = (tid >> 5) * 4;
    float4 wreg[8], xreg;
    float acc[4][8];
    #pragma unroll
    for (int r = 0; r < 4; ++r)
        #pragma unroll
        for (int q = 0; q < 8; ++q) acc[r][q] = 0.f;

    {   // prefetch chunk 0
        int k0 = kbase;
        #pragma unroll
        for (int r = 0; r < 8; ++r) {
            int row = jt + wjr + r * 32;
            if (GATES) {
                int kg = k0 + wkc;
                wreg[r] = (kg < 768) ? *(const float4*)(wih + (size_t)row * 768 + kg)
                                     : *(const float4*)(whh + (size_t)row * 512 + (kg - 768));
            } else {
                if (row >= V_OUT) row = 0;
                wreg[r] = *(const float4*)(Wfull + (size_t)row * 1536 + k0 + wkc);
            }
        }
        xreg = *(const float4*)(X + (size_t)xb * xstride + k0 + xk);
    }
    for (int ch = 0; ch < 8; ++ch) {
        __syncthreads();
        #pragma unroll
        for (int r = 0; r < 8; ++r) {
            Ws[wkc+0][wjr + r*32] = wreg[r].x;
            Ws[wkc+1][wjr + r*32] = wreg[r].y;
            Ws[wkc+2][wjr + r*32] = wreg[r].z;
            Ws[wkc+3][wjr + r*32] = wreg[r].w;
        }
        Xs[xk+0][xb] = xreg.x; Xs[xk+1][xb] = xreg.y;
        Xs[xk+2][xb] = xreg.z; Xs[xk+3][xb] = xreg.w;
        __syncthreads();
        if (ch < 7) {
            int k0 = kbase + (ch + 1) * 32;
            #pragma unroll
            for (int r = 0; r < 8; ++r) {
                int row = jt + wjr + r * 32;
                if (GATES) {
                    int kg = k0 + wkc;
                    wreg[r] = (kg < 768) ? *(const float4*)(wih + (size_t)row * 768 + kg)
                                         : *(const float4*)(whh + (size_t)row * 512 + (kg - 768));
                } else {
                    if (row >= V_OUT) row = 0;
                    wreg[r] = *(const float4*)(Wfull + (size_t)row * 1536 + k0 + wkc);
                }
            }
            xreg = *(const float4*)(X + (size_t)xb * xstride + k0 + xk);
        }
        #pragma unroll 4
        for (int kk = 0; kk < 32; ++kk) {
            float4 xv = *(const float4*)&Xs[kk][bq * 4];
            float4 w0 = *(const float4*)&Ws[kk][jq * 4];
            float4 w1 = *(const float4*)&Ws[kk][128 + jq * 4];
            acc[0][0] += xv.x*w0.x; acc[0][1] += xv.x*w0.y; acc[0][2] += xv.x*w0.z; acc[0][3] += xv.x*w0.w;
            acc[0][4] += xv.x*w1.x; acc[0][5] += xv.x*w1.y; acc[0][6] += xv.x*w1.z; acc[0][7] += xv.x*w1.w;
            acc[1][0] += xv.y*w0.x; acc[1][1] += xv.y*w0.y; acc[1][2] += xv.y*w0.z; acc[1][3] += xv.y*w0.w;
            acc[1][4] += xv.y*w1.x; acc[1][5] += xv.y*w1.y; acc[1][6] += xv.y*w1.z; acc[1][7] += xv.y*w1.w;
            acc[2][0] += xv.z*w0.x; acc[2][1] += xv.z*w0.y; acc[2][2] += xv.z*w0.z; acc[2][3] += xv.z*w0.w;
            acc[2][4] += xv.z*w1.x; acc[2][5] += xv.z*w1.y; acc[2][6] += xv.z*w1.z; acc[2][7] += xv.z*w1.w;
            acc[3][0] += xv.w*w0.x; acc[3][1] += xv.w*w0.y; acc[3][2] += xv.w*w0.z; acc[3][3] += xv.w*w0.w;
            acc[3][4] += xv.w*w1.x; acc[3][5] += xv.w*w1.y; acc[3][6] += xv.w*w1.z; acc[3][7] += xv.w*w1.w;
        }
    }
    #pragma unroll
    for (int r = 0; r < 4; ++r) {
        float* dst = outp + (size_t)(bq * 4 + r) * ostride;
        #pragma unroll
        for (int q = 0; q < 4; ++q) {
            int j1 = jt + jq * 4 + q;
            int j2 = jt + 128 + jq * 4 + q;
            if (GATES) {
                dst[j1] = acc[r][q];
                dst[j2] = acc[r][4 + q];
            } else {
                if (j1 < V_OUT) dst[j1] = acc[r][q];
                if (j2 < V_OUT) dst[j2] = acc[r][4 + q];
            }
        }
    }
}

// ---------------- init: zero hs,c,ctr; xg = [embN[SOS]|embT[SOS]|h=0] ----------
__global__ void k_init(KArgs a) {
    int i = blockIdx.x * 256 + threadIdx.x;
    int gs = gridDim.x * 256;
    for (int k = i; k < BB * LL * 512; k += gs) a.hs[k] = 0.0f;
    for (int k = i; k < BB * 512; k += gs) a.c[k] = 0.0f;
    for (int k = i; k < BB * 1280; k += gs) {
        int kk = k % 1280;
        float v;
        if (kk < 256)      v = a.embN[kk];
        else if (kk < 768) v = a.embT[kk - 256];
        else               v = 0.0f;
        a.xg[k] = v;
    }
    if (i < 16) a.ctr[i] = 0u;
}

// ---------------- mega: all 128 steps, flag-pipelined ---------------------------
__global__ __launch_bounds__(256, 4) void k_mega(KArgs a) {
    __shared__ __align__(16) float smem[9216];   // 36 KB
    const int bx = blockIdx.x;
    const int tid = threadIdx.x;
    unsigned* ctrG  = a.ctr + 0;
    unsigned* ctrC  = a.ctr + 1;
    unsigned* ctrB2 = a.ctr + 2;
    unsigned* ctrS  = a.ctr + 3;

    if (bx < NB_GATES) {
        // ======== prologue: gates(0) from xg built by k_init ========
        const int jb = bx % JBG, sp = bx / JBG;
        gemm_tile<true>(nullptr, a.w_ih, a.w_hh, a.xg, 1280, jb * 256, sp * 256,
                        a.gpart + (size_t)sp * (BB * 2048), 2048, smem, tid);
        signal(ctrG, tid);
        return;
    }
    const int g = bx - NB_GATES;
    const int s = g / GROUP;          // step
    const int r = g % GROUP;

    if (s >= LL) {
        // ======== loss block (very last) ========
        wait_ge(ctrS, 32u * LL, tid);
        float acc = 0.0f;
        for (int i = tid; i < BB * LL; i += 256) acc += a.tl_partial[i];
        smem[tid] = acc;
        __syncthreads();
        for (int st = 128; st > 0; st >>= 1) {
            if (tid < st) smem[tid] += smem[tid + st];
            __syncthreads();
        }
        if (tid == 0) a.out[0] = smem[0];
        return;
    }

    if (r < 32) {
        // ======== cell(s): b = r ========
        // waits: gates(s) done; back(s-1) logits+Wh done (xbuf overwrite hazard)
        wait_ge(ctrG, (unsigned)(NB_GATES * (s + 1)), tid);
        wait_ge(ctrB2, (unsigned)(256 * s), tid);
        float* h_s = smem;          // 512
        float* c_s = smem + 512;    // 512
        float* red = smem + 1024;   // 256
        const int b = r;
        int parent = (s == 0) ? 0 : a.p_t[b * LL + s - 1];
        for (int k = tid; k < 512; k += 256)
            a.xbuf[b * 1536 + 1024 + k] = a.hs[((size_t)b * LL + parent) * 512 + k];
        for (int jj = tid; jj < 512; jj += 256) {
            float ig = a.b_ih[jj]        + a.b_hh[jj];
            float fg = a.b_ih[512 + jj]  + a.b_hh[512 + jj];
            float gg = a.b_ih[1024 + jj] + a.b_hh[1024 + jj];
            float og = a.b_ih[1536 + jj] + a.b_hh[1536 + jj];
            #pragma unroll
            for (int sp = 0; sp < GSG; ++sp) {
                const float* gp = a.gpart + ((size_t)sp * BB + b) * 2048;
                ig += gp[jj]; fg += gp[512 + jj]; gg += gp[1024 + jj]; og += gp[1536 + jj];
            }
            float si = 1.0f / (1.0f + expf(-ig));
            float sf = 1.0f / (1.0f + expf(-fg));
            float so = 1.0f / (1.0f + expf(-og));
            float cn = sf * a.c[b * 512 + jj] + si * tanhf(gg);
            float hn = so * tanhf(cn);
            c_s[jj] = cn; h_s[jj] = hn;
            a.c[b * 512 + jj] = cn;
        }
        __syncthreads();
        int nn = a.n_t[b * LL + s], tn = a.t_t[b * LL + s];  // inputs for step s+1
        for (int k = tid; k < 512; k += 256) {
            float hv = h_s[k], cv = c_s[k];
            a.hs[((size_t)b * LL + s) * 512 + k] = hv;
            a.xbuf[b * 1536 + k] = hv;
            a.xbuf[b * 1536 + 512 + k] = cv;
            a.xg[b * 1280 + 768 + k] = hv;
            a.xg[b * 1280 + 256 + k] = a.embT[(size_t)tn * 512 + k];
        }
        a.xg[b * 1280 + tid] = a.embN[(size_t)nn * 256 + tid];
        float acc = 0.0f;
        for (int k = tid; k < 512; k += 256) acc += h_s[k] * a.Ws_w[k];
        for (int k = tid; k < 512; k += 256) acc += c_s[k] * a.Ws_w[512 + k];
        red[tid] = acc;
        __syncthreads();
        for (int s2 = 128; s2 > 0; s2 >>= 1) {
            if (tid < s2) red[tid] += red[tid + s2];
            __syncthreads();
        }
        if (tid == 0) a.s_t[s * 32 + b] = 1.0f / (1.0f + expf(-(red[0] + a.Ws_b[0])));
        signal(ctrC, tid);
        return;
    }
    if (r < 32 + NB_GATES) {
        // ======== gates(s+1): reads xg written by cell(s) ========
        wait_ge(ctrC, (unsigned)(32 * (s + 1)), tid);
        const int idx = r - 32;
        const int jb = idx % JBG, sp = idx / JBG;
        gemm_tile<true>(nullptr, a.w_ih, a.w_hh, a.xg, 1280, jb * 256, sp * 256,
                        a.gpart + (size_t)sp * (BB * 2048), 2048, smem, tid);
        signal(ctrG, tid);
        return;
    }
    if (r < 32 + NB_GATES + NB_WH) {
        // ======== Wh(s): a_out[b][j] = h[b].Wh_w[j] + Wh_b[j] ========
        wait_ge(ctrC, (unsigned)(32 * (s + 1)), tid);
        wait_ge(ctrS, (unsigned)(32 * s), tid);     // a_out overwrite hazard vs scorefinal(s-1)
        const int j = (r - 32 - NB_GATES) * 32 + (tid & 31);
        const int b0 = (tid >> 5) * 4;
        float ac[4] = {0.f, 0.f, 0.f, 0.f};
        const float* wrow = a.Wh_w + (size_t)j * 512;
        #pragma unroll 4
        for (int k = 0; k < 512; k += 4) {
            float4 w = *(const float4*)(wrow + k);
            #pragma unroll
            for (int q = 0; q < 4; ++q) {
                float4 x = *(const float4*)(a.xbuf + (size_t)(b0 + q) * 1536 + k);
                ac[q] += w.x*x.x + w.y*x.y + w.z*x.z + w.w*x.w;
            }
        }
        float bias = a.Wh_b[j];
        #pragma unroll
        for (int q = 0; q < 4; ++q) a.a_out[(b0 + q) * 512 + j] = ac[q] + bias;
        signal(ctrB2, tid);
        return;
    }
    if (r < 32 + NB_GATES + NB_WH + NB_LOGITS) {
        // ======== logits(s): lpart = xbuf @ Wg^T (split-K) ========
        wait_ge(ctrC, (unsigned)(32 * (s + 1)), tid);
        wait_ge(ctrS, (unsigned)(32 * s), tid);     // lpart overwrite hazard vs scorefinal(s-1)
        const int idx = r - 32 - NB_GATES - NB_WH;
        const int jb = idx % JBL, sp = idx / JBL;
        gemm_tile<false>(a.Wg_w, nullptr, nullptr, a.xbuf, 1536, jb * 256, sp * 256,
                         a.lpart + (size_t)sp * ((size_t)BB * V_OUT), V_OUT, smem, tid);
        signal(ctrB2, tid);
        return;
    }
    {
        // ======== scorefinal(s): b = r - 328 ========
        wait_ge(ctrB2, (unsigned)(256 * (s + 1)), tid);
        float* a_s = smem;                   // 512
        float* sc  = smem + 512;             // 52
        float* mv  = smem + 576;             // 256
        float* sv  = smem + 832;             // 256
        int*   mi  = (int*)(smem + 1088);    // 256
        const int b = r - (32 + NB_GATES + NB_WH + NB_LOGITS);
        const int lane = tid & 63, wv = tid >> 6;
        for (int k = tid; k < 512; k += 256) a_s[k] = a.a_out[b * 512 + k];
        __syncthreads();
        for (int w = wv; w < ATTN; w += 4) {
            int idx = s + w - ATTN;
            int idxc = idx < 0 ? 0 : idx;
            bool mask = (idx < 0) || (a.n_t[b * LL + idxc] == EOF_N);
            float sres = -1e20f;
            if (!mask) {
                const float* mrow = a.hs + ((size_t)b * LL + idxc) * 512;
                float acc = 0.0f;
                for (int k = lane; k < 512; k += 64) {
                    float x = a_s[k] + mrow[k];
                    float e = __expf(2.0f * x);
                    acc += a.v_w[k] * (1.0f - 2.0f / (e + 1.0f));
                }
                for (int o = 32; o > 0; o >>= 1) acc += __shfl_down(acc, o);
                sres = acc + a.v_b[0];
            }
            if (lane == 0) sc[w] = sres;
        }
        __syncthreads();
        if (tid == 0) {
            float m = -INFINITY;
            for (int w = 0; w < ATTN; w++) m = fmaxf(m, sc[w]);
            float Z = 0.0f, emax = 0.0f;
            for (int w = 0; w < ATTN; w++) {
                float e = __expf(sc[w] - m);
                Z += e;
                if (e > emax) emax = e;
            }
            sc[50] = emax / Z;   // amax of attn_w
            sc[51] = 1.0f;       // asum (softmax sums to 1; dead-branch only)
        }
        int t_col = a.t_t[b * LL + s];
        float lmax = -INFINITY; int limax = 0; float lsum = 0.0f;
        for (int j = tid; j < V_OUT; j += 256) {
            float v = a.Wg_b[j];
            #pragma unroll
            for (int sp = 0; sp < GSL; ++sp)
                v += a.lpart[(size_t)sp * ((size_t)BB * V_OUT) + (size_t)b * V_OUT + j];
            lsum += v;
            if (v > lmax) { lmax = v; limax = j; }
            if (j == t_col) smem[1344] = v;
            if (j == EOF_T) smem[1345] = v;
        }
        mv[tid] = lmax; mi[tid] = limax; sv[tid] = lsum;
        __syncthreads();
        for (int s2 = 128; s2 > 0; s2 >>= 1) {
            if (tid < s2) {
                if (mv[tid + s2] > mv[tid] || (mv[tid + s2] == mv[tid] && mi[tid + s2] < mi[tid])) {
                    mv[tid] = mv[tid + s2]; mi[tid] = mi[tid + s2];
                }
                sv[tid] += sv[tid + s2];
            }
            __syncthreads();
        }
        float M = mv[0]; int argJ = mi[0]; float sumL = sv[0];
        __syncthreads();
        float esum = 0.0f;
        for (int j = tid; j < V_OUT; j += 256) {
            float v = a.Wg_b[j];
            #pragma unroll
            for (int sp = 0; sp < GSL; ++sp)
                v += a.lpart[(size_t)sp * ((size_t)BB * V_OUT) + (size_t)b * V_OUT + j];
            esum += expf(v - M);
        }
        sv[tid] = esum;
        __syncthreads();
        for (int s2 = 128; s2 > 0; s2 >>= 1) {
            if (tid < s2) sv[tid] += sv[tid + s2];
            __syncthreads();
        }
        if (tid == 0) {
            float lse = logf(sv[0]);
            float st = a.s_t[s * 32 + b];
            float amax = sc[50], asum = sc[51];
            float max_out = st * (-lse);
            float max_loc = (1.0f - st) * amax;
            bool cond = max_out > max_loc;
            const float CONST_T = CONF * logf(CONF) + 0.1f * logf(SM_VAL);
            float tl; int topi;
            if (!cond) {
                topi = argJ;
                float off = M + lse;
                float out_t = st * (smem[1344] - off);
                float out_e = st * (smem[1345] - off);
                float S = st * (sumL - (float)V_OUT * off);
                tl = CONST_T - (SM_VAL * (S - out_e - out_t) + CONF * out_t);
            } else {
                topi = 0;
                float S = (1.0f - st) * asum;
                tl = CONST_T - SM_VAL * S;
            }
            if (t_col == EOF_T) tl = 0.0f;
            a.tl_partial[s * BB + b] = tl;
            a.out[1 + b * LL + s] = (float)topi;
        }
        signal(ctrS, tid);
        return;
    }
}

extern "C" void kernel_launch(void* const* d_in, const int* in_sizes, int n_in,
                              void* d_out, int out_size, void* d_ws, size_t ws_size,
                              hipStream_t stream) {
    KArgs args;
    args.n_t  = (const int*)d_in[0];
    args.t_t  = (const int*)d_in[1];
    args.p_t  = (const int*)d_in[2];
    args.embN = (const float*)d_in[3];
    args.embT = (const float*)d_in[4];
    args.w_ih = (const float*)d_in[5];
    args.w_hh = (const float*)d_in[6];
    args.b_ih = (const float*)d_in[7];
    args.b_hh = (const float*)d_in[8];
    args.Wh_w = (const float*)d_in[9];
    args.Wh_b = (const float*)d_in[10];
    args.v_w  = (const float*)d_in[11];
    args.v_b  = (const float*)d_in[12];
    args.Wg_w = (const float*)d_in[13];
    args.Wg_b = (const float*)d_in[14];
    args.Ws_w = (const float*)d_in[15];
    args.Ws_b = (const float*)d_in[16];
    args.out  = (float*)d_out;

    // workspace layout (floats)
    float* ws = (float*)d_ws;
    args.hs         = ws;                     // 2,097,152
    args.c          = args.hs + 2097152;      // 16,384
    args.xbuf       = args.c + 16384;         // 49,152   [h|c|hcp] per b
    args.xg         = args.xbuf + 49152;      // 40,960   [embN|embT|h] per b
    args.a_out      = args.xg + 40960;        // 16,384
    args.s_t        = args.a_out + 16384;     // 4,096    per-step s_t
    args.tl_partial = args.s_t + 4096;        // 4,096
    args.gpart      = args.tl_partial + 4096; // 5*32*2048   = 327,680
    args.lpart      = args.gpart + 327680;    // 6*32*10053  = 1,930,176
    args.ctr        = (unsigned*)(args.lpart + 1930176);  // 16 uints
    // total ~ 4,486,096 floats ~ 17.95 MB

    k_init<<<2048, 256, 0, stream>>>(args);
    k_mega<<<NBLOCKS, 256, 0, stream>>>(args);
}

// Round 6
// 16456.895 us; speedup vs baseline: 2.1890x; 1.3605x over previous
//
#include <hip/hip_runtime.h>
#include <math.h>

#define VOCAB_N 300
#define VOCAB_T 10000
#define ATTN 50
#define V_OUT (VOCAB_T + ATTN + 3)   // 10053
#define EOF_N (VOCAB_N - 1)          // 299
#define EOF_T (VOCAB_T - 1)          // 9999
#define SOS 0
#define CONF 0.9f
#define SM_VAL (0.1f / (float)(V_OUT - 2))
#define BB 32
#define LL 128

#define GSG 5                 // gates split-K: K=1280 -> 256/split
#define GSL 6                 // logits split-K: K=1536 -> 256/split
#define JBG 8                 // gates j-blocks (8*256 = 2048)
#define JBL 40                // logits j-blocks (40*256 >= 10053)
#define NB_GATES (JBG*GSG)    // 40
#define NB_WH 16
#define NB_LOGITS (JBL*GSL)   // 240
#define GROUP (32 + NB_GATES + NB_WH + NB_LOGITS + 32)   // 360
#define NBLOCKS (NB_GATES + GROUP*LL + 1)                // 46121

// phase ids for per-step counters (each counter on its own 256B line)
#define PH_G 0   // gates(step) done: 40
#define PH_C 1   // cell(step) done: 32
#define PH_B 2   // logits+Wh(step) done: 256
#define PH_S 3   // scorefinal(step) done: 32
#define CTRN (129 * 4 * 64)   // uints

struct KArgs {
    const int *n_t, *t_t, *p_t;
    const float *embN, *embT, *w_ih, *w_hh, *b_ih, *b_hh;
    const float *Wh_w, *Wh_b, *v_w, *v_b, *Wg_w, *Wg_b, *Ws_w, *Ws_b;
    float *out;
    float *hs, *c, *xbuf, *xg, *a_out, *s_t, *tl_partial, *gpart, *lpart;
    unsigned *ctr;
};

__device__ __forceinline__ unsigned* ctr_at(unsigned* base, int s, int ph) {
    return base + ((((unsigned)s << 2) + (unsigned)ph) << 6);   // 64 uints = 256B apart
}

// consumer: immediate check (fast path), then backoff poll; acquire fence on exit
__device__ __forceinline__ void wait_eq(unsigned* p, unsigned target, int tid) {
    if (tid == 0) {
        if (target > 0) {
            unsigned v = __hip_atomic_load(p, __ATOMIC_RELAXED, __HIP_MEMORY_SCOPE_AGENT);
            int tries = 0;
            while (v < target) {
                if (tries < 8) { __builtin_amdgcn_s_sleep(4); ++tries; }
                else           { __builtin_amdgcn_s_sleep(64); }
                v = __hip_atomic_load(p, __ATOMIC_RELAXED, __HIP_MEMORY_SCOPE_AGENT);
            }
        }
        __threadfence();   // acquire: invalidate stale L1/L2
    }
    __syncthreads();
}

// producer: drain block stores, release fence (L2 wb), device-scope signal
__device__ __forceinline__ void signal(unsigned* p, int tid) {
    __syncthreads();
    if (tid == 0) { __threadfence(); atomicAdd(p, 1u); }
}

// ---- GEMM tile: BN=256 j x 32 b, 8 chunks of K=32 (proven R3-R5 body) ----
// W chunk-0 prefetch happens BEFORE the data wait (weights are step-invariant);
// store-WAR wait (sctr) deferred to just before the output stores.
template<bool GATES>
__device__ __forceinline__ void gemm_tile(
        const float* __restrict__ Wfull,
        const float* __restrict__ wih, const float* __restrict__ whh,
        const float* __restrict__ X, const int xstride,
        const int jt, const int kbase,
        float* __restrict__ outp, const int ostride,
        float* smem, const int tid,
        unsigned* wctr, unsigned wtarget,
        unsigned* sctr, unsigned starget) {
    float (*Ws)[256] = (float(*)[256])smem;             // 32 x 256
    float (*Xs)[32]  = (float(*)[32])(smem + 8192);     // 32 x 32
    const int jq = tid & 31;
    const int bq = tid >> 5;
    const int wjr = tid & 31, wkc = (tid >> 5) * 4;
    const int xb  = tid & 31, xk  = (tid >> 5) * 4;
    float4 wreg[8], xreg;
    float acc[4][8];
    #pragma unroll
    for (int r = 0; r < 4; ++r)
        #pragma unroll
        for (int q = 0; q < 8; ++q) acc[r][q] = 0.f;

    {   // prefetch W chunk 0 (no dependence on step data)
        int k0 = kbase;
        #pragma unroll
        for (int r = 0; r < 8; ++r) {
            int row = jt + wjr + r * 32;
            if (GATES) {
                int kg = k0 + wkc;
                wreg[r] = (kg < 768) ? *(const float4*)(wih + (size_t)row * 768 + kg)
                                     : *(const float4*)(whh + (size_t)row * 512 + (kg - 768));
            } else {
                if (row >= V_OUT) row = 0;
                wreg[r] = *(const float4*)(Wfull + (size_t)row * 1536 + k0 + wkc);
            }
        }
    }
    wait_eq(wctr, wtarget, tid);          // data-ready (X producer) wait
    xreg = *(const float4*)(X + (size_t)xb * xstride + kbase + xk);

    for (int ch = 0; ch < 8; ++ch) {
        __syncthreads();
        #pragma unroll
        for (int r = 0; r < 8; ++r) {
            Ws[wkc+0][wjr + r*32] = wreg[r].x;
            Ws[wkc+1][wjr + r*32] = wreg[r].y;
            Ws[wkc+2][wjr + r*32] = wreg[r].z;
            Ws[wkc+3][wjr + r*32] = wreg[r].w;
        }
        Xs[xk+0][xb] = xreg.x; Xs[xk+1][xb] = xreg.y;
        Xs[xk+2][xb] = xreg.z; Xs[xk+3][xb] = xreg.w;
        __syncthreads();
        if (ch < 7) {
            int k0 = kbase + (ch + 1) * 32;
            #pragma unroll
            for (int r = 0; r < 8; ++r) {
                int row = jt + wjr + r * 32;
                if (GATES) {
                    int kg = k0 + wkc;
                    wreg[r] = (kg < 768) ? *(const float4*)(wih + (size_t)row * 768 + kg)
                                         : *(const float4*)(whh + (size_t)row * 512 + (kg - 768));
                } else {
                    if (row >= V_OUT) row = 0;
                    wreg[r] = *(const float4*)(Wfull + (size_t)row * 1536 + k0 + wkc);
                }
            }
            xreg = *(const float4*)(X + (size_t)xb * xstride + k0 + xk);
        }
        #pragma unroll 4
        for (int kk = 0; kk < 32; ++kk) {
            float4 xv = *(const float4*)&Xs[kk][bq * 4];
            float4 w0 = *(const float4*)&Ws[kk][jq * 4];
            float4 w1 = *(const float4*)&Ws[kk][128 + jq * 4];
            acc[0][0] += xv.x*w0.x; acc[0][1] += xv.x*w0.y; acc[0][2] += xv.x*w0.z; acc[0][3] += xv.x*w0.w;
            acc[0][4] += xv.x*w1.x; acc[0][5] += xv.x*w1.y; acc[0][6] += xv.x*w1.z; acc[0][7] += xv.x*w1.w;
            acc[1][0] += xv.y*w0.x; acc[1][1] += xv.y*w0.y; acc[1][2] += xv.y*w0.z; acc[1][3] += xv.y*w0.w;
            acc[1][4] += xv.y*w1.x; acc[1][5] += xv.y*w1.y; acc[1][6] += xv.y*w1.z; acc[1][7] += xv.y*w1.w;
            acc[2][0] += xv.z*w0.x; acc[2][1] += xv.z*w0.y; acc[2][2] += xv.z*w0.z; acc[2][3] += xv.z*w0.w;
            acc[2][4] += xv.z*w1.x; acc[2][5] += xv.z*w1.y; acc[2][6] += xv.z*w1.z; acc[2][7] += xv.z*w1.w;
            acc[3][0] += xv.w*w0.x; acc[3][1] += xv.w*w0.y; acc[3][2] += xv.w*w0.z; acc[3][3] += xv.w*w0.w;
            acc[3][4] += xv.w*w1.x; acc[3][5] += xv.w*w1.y; acc[3][6] += xv.w*w1.z; acc[3][7] += xv.w*w1.w;
        }
    }
    if (starget > 0) wait_eq(sctr, starget, tid);   // WAR: old-buffer readers done
    #pragma unroll
    for (int r = 0; r < 4; ++r) {
        float* dst = outp + (size_t)(bq * 4 + r) * ostride;
        #pragma unroll
        for (int q = 0; q < 4; ++q) {
            int j1 = jt + jq * 4 + q;
            int j2 = jt + 128 + jq * 4 + q;
            if (GATES) {
                dst[j1] = acc[r][q];
                dst[j2] = acc[r][4 + q];
            } else {
                if (j1 < V_OUT) dst[j1] = acc[r][q];
                if (j2 < V_OUT) dst[j2] = acc[r][4 + q];
            }
        }
    }
}

// ---------------- init: zero hs,c,ctr; xg = [embN[SOS]|embT[SOS]|h=0] ----------
__global__ void k_init(KArgs a) {
    int i = blockIdx.x * 256 + threadIdx.x;
    int gs = gridDim.x * 256;
    for (int k = i; k < BB * LL * 512; k += gs) a.hs[k] = 0.0f;
    for (int k = i; k < BB * 512; k += gs) a.c[k] = 0.0f;
    for (int k = i; k < BB * 1280; k += gs) {
        int kk = k % 1280;
        float v;
        if (kk < 256)      v = a.embN[kk];
        else if (kk < 768) v = a.embT[kk - 256];
        else               v = 0.0f;
        a.xg[k] = v;
    }
    for (int k = i; k < CTRN; k += gs) a.ctr[k] = 0u;
}

// ---------------- mega: all 128 steps, flag-pipelined ---------------------------
__global__ __launch_bounds__(256, 4) void k_mega(KArgs a) {
    __shared__ __align__(16) float smem[9216];   // 36 KB
    const int bx = blockIdx.x;
    const int tid = threadIdx.x;

    if (bx < NB_GATES) {
        // ======== prologue: gates(0) from xg built by k_init ========
        const int jb = bx % JBG, sp = bx / JBG;
        gemm_tile<true>(nullptr, a.w_ih, a.w_hh, a.xg, 1280, jb * 256, sp * 256,
                        a.gpart + (size_t)sp * (BB * 2048), 2048, smem, tid,
                        ctr_at(a.ctr, 0, PH_G), 0u, nullptr, 0u);
        signal(ctr_at(a.ctr, 0, PH_G), tid);
        return;
    }
    const int g = bx - NB_GATES;
    const int s = g / GROUP;          // step
    const int r = g % GROUP;

    if (s >= LL) {
        // ======== loss block (very last) ========
        for (int q = 0; q < LL; ++q) wait_eq(ctr_at(a.ctr, q, PH_S), 32u, tid);
        float acc = 0.0f;
        for (int i = tid; i < BB * LL; i += 256) acc += a.tl_partial[i];
        smem[tid] = acc;
        __syncthreads();
        for (int st = 128; st > 0; st >>= 1) {
            if (tid < st) smem[tid] += smem[tid + st];
            __syncthreads();
        }
        if (tid == 0) a.out[0] = smem[0];
        return;
    }

    if (r < 32) {
        // ======== cell(s): b = r ========
        wait_eq(ctr_at(a.ctr, s, PH_G), (unsigned)NB_GATES, tid);   // gpart ready
        float* h_s = smem;          // 512
        float* c_s = smem + 512;    // 512
        float* p_s = smem + 1024;   // 512 (hcp snapshot)
        float* red = smem + 1536;   // 256
        const int b = r;
        int parent = (s == 0) ? 0 : a.p_t[b * LL + s - 1];
        // snapshot hs[parent] into LDS (xbuf write deferred; parent<=s-1 or zeros)
        for (int k = tid; k < 512; k += 256)
            p_s[k] = a.hs[((size_t)b * LL + parent) * 512 + k];
        for (int jj = tid; jj < 512; jj += 256) {
            float ig = a.b_ih[jj]        + a.b_hh[jj];
            float fg = a.b_ih[512 + jj]  + a.b_hh[512 + jj];
            float gg = a.b_ih[1024 + jj] + a.b_hh[1024 + jj];
            float og = a.b_ih[1536 + jj] + a.b_hh[1536 + jj];
            #pragma unroll
            for (int sp = 0; sp < GSG; ++sp) {
                const float* gp = a.gpart + ((size_t)sp * BB + b) * 2048;
                ig += gp[jj]; fg += gp[512 + jj]; gg += gp[1024 + jj]; og += gp[1536 + jj];
            }
            float si = 1.0f / (1.0f + expf(-ig));
            float sf = 1.0f / (1.0f + expf(-fg));
            float so = 1.0f / (1.0f + expf(-og));
            float cn = sf * a.c[b * 512 + jj] + si * tanhf(gg);
            float hn = so * tanhf(cn);
            c_s[jj] = cn; h_s[jj] = hn;
            a.c[b * 512 + jj] = cn;
            a.hs[((size_t)b * LL + s) * 512 + jj] = hn;   // slot s: append-only, no WAR
        }
        __syncthreads();
        // s_t (per-step slot: no WAR)
        {
            float acc = 0.0f;
            for (int k = tid; k < 512; k += 256) acc += h_s[k] * a.Ws_w[k];
            for (int k = tid; k < 512; k += 256) acc += c_s[k] * a.Ws_w[512 + k];
            red[tid] = acc;
            __syncthreads();
            for (int s2 = 128; s2 > 0; s2 >>= 1) {
                if (tid < s2) red[tid] += red[tid + s2];
                __syncthreads();
            }
            if (tid == 0) a.s_t[s * 32 + b] = 1.0f / (1.0f + expf(-(red[0] + a.Ws_b[0])));
        }
        // WAR: xbuf/xg still being read by logits/Wh(s-1)
        if (s > 0) wait_eq(ctr_at(a.ctr, s - 1, PH_B), (unsigned)(NB_WH + NB_LOGITS), tid);
        int nn = a.n_t[b * LL + s], tn = a.t_t[b * LL + s];  // inputs for step s+1
        for (int k = tid; k < 512; k += 256) {
            float hv = h_s[k], cv = c_s[k];
            a.xbuf[b * 1536 + k] = hv;
            a.xbuf[b * 1536 + 512 + k] = cv;
            a.xbuf[b * 1536 + 1024 + k] = p_s[k];
            a.xg[b * 1280 + 768 + k] = hv;
            a.xg[b * 1280 + 256 + k] = a.embT[(size_t)tn * 512 + k];
        }
        a.xg[b * 1280 + tid] = a.embN[(size_t)nn * 256 + tid];
        signal(ctr_at(a.ctr, s, PH_C), tid);
        return;
    }
    if (r < 32 + NB_GATES) {
        // ======== gates(s+1): reads xg written by cell(s); gpart WAR covered by celldone ==
        const int idx = r - 32;
        const int jb = idx % JBG, sp = idx / JBG;
        gemm_tile<true>(nullptr, a.w_ih, a.w_hh, a.xg, 1280, jb * 256, sp * 256,
                        a.gpart + (size_t)sp * (BB * 2048), 2048, smem, tid,
                        ctr_at(a.ctr, s, PH_C), 32u, nullptr, 0u);
        signal(ctr_at(a.ctr, s + 1, PH_G), tid);
        return;
    }
    if (r < 32 + NB_GATES + NB_WH) {
        // ======== Wh(s): a_out[b][j] = h[b].Wh_w[j] + Wh_b[j] ========
        const int j = (r - 32 - NB_GATES) * 32 + (tid & 31);
        const int b0 = (tid >> 5) * 4;
        const float* wrow = a.Wh_w + (size_t)j * 512;
        // prefetch first weight row segment before wait (step-invariant)
        float4 w0pre = *(const float4*)(wrow);
        wait_eq(ctr_at(a.ctr, s, PH_C), 32u, tid);
        float ac[4] = {0.f, 0.f, 0.f, 0.f};
        {
            float4 w = w0pre;
            #pragma unroll
            for (int q = 0; q < 4; ++q) {
                float4 x = *(const float4*)(a.xbuf + (size_t)(b0 + q) * 1536);
                ac[q] += w.x*x.x + w.y*x.y + w.z*x.z + w.w*x.w;
            }
        }
        #pragma unroll 4
        for (int k = 4; k < 512; k += 4) {
            float4 w = *(const float4*)(wrow + k);
            #pragma unroll
            for (int q = 0; q < 4; ++q) {
                float4 x = *(const float4*)(a.xbuf + (size_t)(b0 + q) * 1536 + k);
                ac[q] += w.x*x.x + w.y*x.y + w.z*x.z + w.w*x.w;
            }
        }
        float bias = a.Wh_b[j];
        // WAR: a_out still read by scorefinal(s-1)
        if (s > 0) wait_eq(ctr_at(a.ctr, s - 1, PH_S), 32u, tid);
        #pragma unroll
        for (int q = 0; q < 4; ++q) a.a_out[(b0 + q) * 512 + j] = ac[q] + bias;
        signal(ctr_at(a.ctr, s, PH_B), tid);
        return;
    }
    if (r < 32 + NB_GATES + NB_WH + NB_LOGITS) {
        // ======== logits(s): lpart = xbuf @ Wg^T (split-K) ========
        const int idx = r - 32 - NB_GATES - NB_WH;
        const int jb = idx % JBL, sp = idx / JBL;
        gemm_tile<false>(a.Wg_w, nullptr, nullptr, a.xbuf, 1536, jb * 256, sp * 256,
                         a.lpart + (size_t)sp * ((size_t)BB * V_OUT), V_OUT, smem, tid,
                         ctr_at(a.ctr, s, PH_C), 32u,
                         (s > 0) ? ctr_at(a.ctr, s - 1, PH_S) : nullptr, (s > 0) ? 32u : 0u);
        signal(ctr_at(a.ctr, s, PH_B), tid);
        return;
    }
    {
        // ======== scorefinal(s): b = r - 328 ========
        wait_eq(ctr_at(a.ctr, s, PH_B), (unsigned)(NB_WH + NB_LOGITS), tid);
        float* a_s = smem;                   // 512
        float* sc  = smem + 512;             // 52
        float* mv  = smem + 576;             // 256
        float* sv  = smem + 832;             // 256
        int*   mi  = (int*)(smem + 1088);    // 256
        const int b = r - (32 + NB_GATES + NB_WH + NB_LOGITS);
        const int lane = tid & 63, wv = tid >> 6;
        for (int k = tid; k < 512; k += 256) a_s[k] = a.a_out[b * 512 + k];
        __syncthreads();
        for (int w = wv; w < ATTN; w += 4) {
            int idx = s + w - ATTN;
            int idxc = idx < 0 ? 0 : idx;
            bool mask = (idx < 0) || (a.n_t[b * LL + idxc] == EOF_N);
            float sres = -1e20f;
            if (!mask) {
                const float* mrow = a.hs + ((size_t)b * LL + idxc) * 512;
                float acc = 0.0f;
                for (int k = lane; k < 512; k += 64) {
                    float x = a_s[k] + mrow[k];
                    float e = __expf(2.0f * x);
                    acc += a.v_w[k] * (1.0f - 2.0f / (e + 1.0f));
                }
                for (int o = 32; o > 0; o >>= 1) acc += __shfl_down(acc, o);
                sres = acc + a.v_b[0];
            }
            if (lane == 0) sc[w] = sres;
        }
        __syncthreads();
        if (tid == 0) {
            float m = -INFINITY;
            for (int w = 0; w < ATTN; w++) m = fmaxf(m, sc[w]);
            float Z = 0.0f, emax = 0.0f;
            for (int w = 0; w < ATTN; w++) {
                float e = __expf(sc[w] - m);
                Z += e;
                if (e > emax) emax = e;
            }
            sc[50] = emax / Z;   // amax of attn_w
            sc[51] = 1.0f;       // asum (dead-branch only)
        }
        int t_col = a.t_t[b * LL + s];
        float lmax = -INFINITY; int limax = 0; float lsum = 0.0f;
        for (int j = tid; j < V_OUT; j += 256) {
            float v = a.Wg_b[j];
            #pragma unroll
            for (int sp = 0; sp < GSL; ++sp)
                v += a.lpart[(size_t)sp * ((size_t)BB * V_OUT) + (size_t)b * V_OUT + j];
            lsum += v;
            if (v > lmax) { lmax = v; limax = j; }
            if (j == t_col) smem[1344] = v;
            if (j == EOF_T) smem[1345] = v;
        }
        mv[tid] = lmax; mi[tid] = limax; sv[tid] = lsum;
        __syncthreads();
        for (int s2 = 128; s2 > 0; s2 >>= 1) {
            if (tid < s2) {
                if (mv[tid + s2] > mv[tid] || (mv[tid + s2] == mv[tid] && mi[tid + s2] < mi[tid])) {
                    mv[tid] = mv[tid + s2]; mi[tid] = mi[tid + s2];
                }
                sv[tid] += sv[tid + s2];
            }
            __syncthreads();
        }
        float M = mv[0]; int argJ = mi[0]; float sumL = sv[0];
        __syncthreads();
        float esum = 0.0f;
        for (int j = tid; j < V_OUT; j += 256) {
            float v = a.Wg_b[j];
            #pragma unroll
            for (int sp = 0; sp < GSL; ++sp)
                v += a.lpart[(size_t)sp * ((size_t)BB * V_OUT) + (size_t)b * V_OUT + j];
            esum += expf(v - M);
        }
        sv[tid] = esum;
        __syncthreads();
        for (int s2 = 128; s2 > 0; s2 >>= 1) {
            if (tid < s2) sv[tid] += sv[tid + s2];
            __syncthreads();
        }
        if (tid == 0) {
            float lse = logf(sv[0]);
            float st = a.s_t[s * 32 + b];
            float amax = sc[50], asum = sc[51];
            float max_out = st * (-lse);
            float max_loc = (1.0f - st) * amax;
            bool cond = max_out > max_loc;
            const float CONST_T = CONF * logf(CONF) + 0.1f * logf(SM_VAL);
            float tl; int topi;
            if (!cond) {
                topi = argJ;
                float off = M + lse;
                float out_t = st * (smem[1344] - off);
                float out_e = st * (smem[1345] - off);
                float S = st * (sumL - (float)V_OUT * off);
                tl = CONST_T - (SM_VAL * (S - out_e - out_t) + CONF * out_t);
            } else {
                topi = 0;
                float S = (1.0f - st) * asum;
                tl = CONST_T - SM_VAL * S;
            }
            if (t_col == EOF_T) tl = 0.0f;
            a.tl_partial[s * BB + b] = tl;
            a.out[1 + b * LL + s] = (float)topi;
        }
        signal(ctr_at(a.ctr, s, PH_S), tid);
        return;
    }
}

extern "C" void kernel_launch(void* const* d_in, const int* in_sizes, int n_in,
                              void* d_out, int out_size, void* d_ws, size_t ws_size,
                              hipStream_t stream) {
    KArgs args;
    args.n_t  = (const int*)d_in[0];
    args.t_t  = (const int*)d_in[1];
    args.p_t  = (const int*)d_in[2];
    args.embN = (const float*)d_in[3];
    args.embT = (const float*)d_in[4];
    args.w_ih = (const float*)d_in[5];
    args.w_hh = (const float*)d_in[6];
    args.b_ih = (const float*)d_in[7];
    args.b_hh = (const float*)d_in[8];
    args.Wh_w = (const float*)d_in[9];
    args.Wh_b = (const float*)d_in[10];
    args.v_w  = (const float*)d_in[11];
    args.v_b  = (const float*)d_in[12];
    args.Wg_w = (const float*)d_in[13];
    args.Wg_b = (const float*)d_in[14];
    args.Ws_w = (const float*)d_in[15];
    args.Ws_b = (const float*)d_in[16];
    args.out  = (float*)d_out;

    // workspace layout (floats)
    float* ws = (float*)d_ws;
    args.hs         = ws;                     // 2,097,152
    args.c          = args.hs + 2097152;      // 16,384
    args.xbuf       = args.c + 16384;         // 49,152   [h|c|hcp] per b
    args.xg         = args.xbuf + 49152;      // 40,960   [embN|embT|h] per b
    args.a_out      = args.xg + 40960;        // 16,384
    args.s_t        = args.a_out + 16384;     // 4,096    per-step
    args.tl_partial = args.s_t + 4096;        // 4,096
    args.gpart      = args.tl_partial + 4096; // 5*32*2048   = 327,680
    args.lpart      = args.gpart + 327680;    // 6*32*10053  = 1,930,176
    args.ctr        = (unsigned*)(args.lpart + 1930176);  // CTRN = 33,024 uints
    // total ~ 4,519,120 floats ~ 18.1 MB

    k_init<<<2048, 256, 0, stream>>>(args);
    k_mega<<<NBLOCKS, 256, 0, stream>>>(args);
}